// Round 17
// baseline (53.077 us; speedup 1.0000x reference)
//
#include <hip/hip_runtime.h>
#include <hip/hip_bf16.h>

namespace {
constexpr int kB = 2, kW = 5, kS = 5, kQ = 75, kC = 64, kHW = 441;
constexpr int kNP = 448;   // support positions padded (14 * 32)
constexpr int kMP = 448;   // query positions padded
constexpr int kCHUNK = 112;
constexpr int kLDT = 65;
constexpr int kTiles = kB * kQ * kW;              // 750
constexpr int kPrepGrid = 8 * 81;

typedef short bf16x8 __attribute__((ext_vector_type(8)));
typedef float f32x16 __attribute__((ext_vector_type(16)));
}

// ---- prep (R15-validated, unchanged): XCD-co-located shot-mean + L2-norm + transpose ----
__global__ __launch_bounds__(256) void prep_k(const float* __restrict__ sup,
                                              const float* __restrict__ qry,
                                              unsigned short* __restrict__ snT,
                                              unsigned short* __restrict__ qnT) {
  __shared__ float img_t[kCHUNK * kLDT];
  __shared__ float inv[kCHUNK];
  const int tid = threadIdx.x;
  const int x = blockIdx.x & 7;
  const int j = blockIdx.x >> 3;

  const int start0 = (x < 6) ? 94 * x : 564 + 93 * (x - 6);
  const int start1 = (x + 1 < 6) ? 94 * (x + 1) : 564 + 93 * (x + 1 - 6);
  const int lo = (start0 + 4) / 5, hi = (start1 + 4) / 5;
  const int nq = 4 * (hi - lo);

  bool is_sup;
  int bw = 0, bq = 0, chunk;
  if (j < nq) {
    is_sup = false;
    bq = lo + (j >> 2);
    chunk = j & 3;
  } else {
    int js = j - nq;
    if (js >= 5) return;
    is_sup = true;
    int u = x + 8 * js;
    bw = u >> 2;
    chunk = u & 3;
  }

  const int m0 = chunk * kCHUNK;
  const int mcnt = min(kCHUNK, kHW - m0);
  unsigned short* dst;

  if (is_sup) {
    const float* base = sup + (size_t)bw * kS * kC * kHW;
    for (int i = tid; i < kC * kCHUNK; i += 256) {
      int c = i / kCHUNK, mm = i % kCHUNK;
      float v = 0.f;
      if (mm < mcnt) {
        const float* p = base + (size_t)c * kHW + m0 + mm;
        float s = 0.f;
#pragma unroll
        for (int k = 0; k < kS; ++k) s += p[(size_t)k * kC * kHW];
        v = s * (1.f / kS);
      }
      img_t[mm * kLDT + c] = v;
    }
    dst = snT + (size_t)bw * kNP * kC;
  } else {
    const float* base = qry + (size_t)bq * kC * kHW;
    for (int i = tid; i < kC * kCHUNK; i += 256) {
      int c = i / kCHUNK, mm = i % kCHUNK;
      img_t[mm * kLDT + c] = (mm < mcnt) ? base[(size_t)c * kHW + m0 + mm] : 0.f;
    }
    dst = qnT + (size_t)bq * kMP * kC;
  }
  __syncthreads();

  if (tid < kCHUNK) {
    float ss = 0.f;
#pragma unroll
    for (int c = 0; c < kC; ++c) { float v = img_t[tid * kLDT + c]; ss += v * v; }
    inv[tid] = 1.f / fmaxf(sqrtf(ss), 1e-12f);
  }
  __syncthreads();

  for (int i8 = tid; i8 < kCHUNK * 8; i8 += 256) {
    int m = i8 >> 3, c8 = (i8 & 7) * 8;
    float sc = inv[m];
    union { unsigned short u[8]; uint4 v; } pk;
#pragma unroll
    for (int jj = 0; jj < 8; ++jj) {
      __hip_bfloat16 o = __float2bfloat16(img_t[m * kLDT + c8 + jj] * sc);
      pk.u[jj] = *reinterpret_cast<unsigned short*>(&o);
    }
    *reinterpret_cast<uint4*>(dst + ((size_t)(m0 + m) * kC + c8)) = pk.v;
  }
}

// ---- max helpers (validated; no inline asm on MFMA outputs — R12 lesson) ----
__device__ __forceinline__ float max16_v(const f32x16& a) {
  float m0 = fmaxf(fmaxf(a[0], a[1]), a[2]);
  float m1 = fmaxf(fmaxf(a[3], a[4]), a[5]);
  float m2 = fmaxf(fmaxf(a[6], a[7]), a[8]);
  float m3 = fmaxf(fmaxf(a[9], a[10]), a[11]);
  float m4 = fmaxf(fmaxf(a[12], a[13]), a[14]);
  return fmaxf(fmaxf(fmaxf(m0, m1), m2), fmaxf(fmaxf(m3, m4), a[15]));
}
__device__ __forceinline__ float max12_v(const f32x16& a) {
  float m0 = fmaxf(fmaxf(a[0], a[1]), a[2]);
  float m1 = fmaxf(fmaxf(a[3], a[4]), a[5]);
  float m2 = fmaxf(fmaxf(a[6], a[7]), a[8]);
  float m3 = fmaxf(fmaxf(a[9], a[10]), a[11]);
  return fmaxf(fmaxf(m0, m1), fmaxf(m2, m3));
}

// load one nt's A-fragments straight from global (R10-validated addressing)
__device__ __forceinline__ void ldA(bf16x8 af[4], const unsigned short* arow, int nt) {
  const unsigned short* p = arow + (size_t)nt * 32 * kC;
#pragma unroll
  for (int kk = 0; kk < 4; ++kk)
    af[kk] = *reinterpret_cast<const bf16x8*>(p + kk * 16);
}

// one nt-tile of MFMAs + row-max; TAIL masks pad rows 441..447
template <bool TAIL>
__device__ __forceinline__ void do_nt(const bf16x8 af[4], const bf16x8 bf[4][4],
                                      int nct, int lh, float rm[4]) {
  f32x16 z;
#pragma unroll
  for (int r = 0; r < 16; ++r) z[r] = 0.f;
#pragma unroll
  for (int ct = 0; ct < 4; ++ct) {
    if (ct < nct) {
      f32x16 acc = z;
#pragma unroll
      for (int kk = 0; kk < 4; ++kk)
        acc = __builtin_amdgcn_mfma_f32_32x32x16_bf16(af[kk], bf[ct][kk], acc, 0, 0, 0);
      if (!TAIL) {
        rm[ct] = fmaxf(rm[ct], max16_v(acc));
      } else {
        // rows 416..447; valid < 441 -> tile row <= 24.
        // row = (r&3)+8*(r>>2)+4*lh: lh0 invalid regs {13,14,15}, lh1 {12..15}
        float t = max12_v(acc);
        if (lh == 0) t = fmaxf(t, acc[12]);  // row 24 still valid
        rm[ct] = fmaxf(rm[ct], t);
      }
    }
  }
}

// ---- main: NO LDS, no staging, no mid-kernel barriers. A-fragments stream
//      from L2 (XCD-co-located) with 1-deep ping-pong prefetch (static a0/a1 —
//      rule #20). bf register-pinned via empty asm "+v" keep-alives so the
//      compiler cannot rematerialize the loads inside the loop (R10's failure:
//      VGPR_Count 36 -> bf reloaded every nt -> latency-bound at 15% MfmaUtil).
//      4 waves x 4 col-tiles halves redundant A-traffic vs 7-wave. ----
__global__ __launch_bounds__(256) void dn4_main_k(const unsigned short* __restrict__ qnT,
                                                  const unsigned short* __restrict__ snT,
                                                  float* __restrict__ out) {
  __shared__ float part[4];
  const int tid = threadIdx.x;

  // bijective XCD-chunked mapping (750 = 6*94 + 2*93)
  const int xcd = blockIdx.x & 7, jj = blockIdx.x >> 3;
  const int idx = (xcd < 6) ? xcd * 94 + jj : 564 + (xcd - 6) * 93 + jj;

  const int w = idx % kW;
  const int bq = idx / kW;
  const int b = bq / kQ;

  const int lane = tid & 63;
  const int lh = lane >> 5;
  const int lm = lane & 31;
  const int wid = tid >> 6;                              // 0..3
  const int ct0 = (wid < 2) ? wid * 4 : 8 + (wid - 2) * 3;  // col-tiles {4,4,3,3}
  const int nct = (wid < 2) ? 4 : 3;

  const unsigned short* sb = snT + (size_t)(b * kW + w) * kNP * kC;
  const unsigned short* qb = qnT + (size_t)bq * kMP * kC;

  // query fragments, register-pinned
  bf16x8 bf[4][4];
#pragma unroll
  for (int ct = 0; ct < 4; ++ct) {
    if (ct < nct) {
      int m = (ct0 + ct) * 32 + lm;
#pragma unroll
      for (int kk = 0; kk < 4; ++kk) {
        bf[ct][kk] = *reinterpret_cast<const bf16x8*>(qb + (size_t)m * kC + kk * 16 + lh * 8);
        asm volatile("" : "+v"(bf[ct][kk]));   // pin: forbid rematerialization
      }
    }
  }

  // per-lane A base: row lm, K-chunk lh (byte layout validated R10)
  const unsigned short* arow = sb + (size_t)lm * kC + lh * 8;

  float rm[4] = {-INFINITY, -INFINITY, -INFINITY, -INFINITY};
  bf16x8 a0[4], a1[4];
  ldA(a0, arow, 0);

  // ping-pong over nt pairs: prefetch next while computing current (static idx)
#pragma unroll 1
  for (int t = 0; t < 6; ++t) {
    ldA(a1, arow, 2 * t + 1);
    do_nt<false>(a0, bf, nct, lh, rm);
    ldA(a0, arow, 2 * t + 2);
    do_nt<false>(a1, bf, nct, lh, rm);
  }
  ldA(a1, arow, 13);
  do_nt<false>(a0, bf, nct, lh, rm);   // nt = 12
  do_nt<true>(a1, bf, nct, lh, rm);    // nt = 13 (masked tail)

  // combine complementary row-halves, then sum this wave's columns
  float s = 0.f;
#pragma unroll
  for (int ct = 0; ct < 4; ++ct) {
    if (ct < nct) s += fmaxf(rm[ct], __shfl_xor(rm[ct], 32, 64));
  }
#pragma unroll
  for (int off = 1; off < 32; off <<= 1) s += __shfl_xor(s, off, 64);

  if (lane == 0) part[wid] = s;
  __syncthreads();
  if (tid == 0) out[idx] = part[0] + part[1] + part[2] + part[3];
}

extern "C" void kernel_launch(void* const* d_in, const int* in_sizes, int n_in,
                              void* d_out, int out_size, void* d_ws, size_t ws_size,
                              hipStream_t stream) {
  const float* sup = (const float*)d_in[0];
  const float* qry = (const float*)d_in[2];
  float* out = (float*)d_out;

  unsigned short* snT = (unsigned short*)d_ws;                 // 573,440 B
  unsigned short* qnT = snT + (size_t)kB * kW * kNP * kC;      // 8,601,600 B

  prep_k<<<kPrepGrid, 256, 0, stream>>>(sup, qry, snT, qnT);
  dn4_main_k<<<kTiles, 256, 0, stream>>>(qnT, snT, out);
}

// Round 18
// 44.007 us; speedup vs baseline: 1.2061x; 1.2061x over previous
//
#include <hip/hip_runtime.h>
#include <hip/hip_bf16.h>

namespace {
constexpr int kB = 2, kW = 5, kS = 5, kQ = 75, kC = 64, kHW = 441;
constexpr int kNP = 448;   // support positions padded (14 * 32)
constexpr int kMP = 448;   // query positions padded
constexpr int kCHUNK = 112;
constexpr int kLDT = 65;
constexpr int kPrepGrid = 8 * 81;
constexpr int kSPerBW = 19;                       // ceil(75/4) q-quads per (b,w)
constexpr int kGrid = kB * kW * kSPerBW;          // 190 blocks -> single generation

typedef short bf16x8 __attribute__((ext_vector_type(8)));
typedef float f32x16 __attribute__((ext_vector_type(16)));
typedef __attribute__((address_space(3))) unsigned int lds_u32;
typedef const __attribute__((address_space(1))) unsigned int gbl_u32;
}

// ---- prep (R15-validated, unchanged): XCD-co-located shot-mean + L2-norm + transpose ----
__global__ __launch_bounds__(256) void prep_k(const float* __restrict__ sup,
                                              const float* __restrict__ qry,
                                              unsigned short* __restrict__ snT,
                                              unsigned short* __restrict__ qnT) {
  __shared__ float img_t[kCHUNK * kLDT];
  __shared__ float inv[kCHUNK];
  const int tid = threadIdx.x;
  const int x = blockIdx.x & 7;
  const int j = blockIdx.x >> 3;

  const int start0 = (x < 6) ? 94 * x : 564 + 93 * (x - 6);
  const int start1 = (x + 1 < 6) ? 94 * (x + 1) : 564 + 93 * (x + 1 - 6);
  const int lo = (start0 + 4) / 5, hi = (start1 + 4) / 5;
  const int nq = 4 * (hi - lo);

  bool is_sup;
  int bw = 0, bq = 0, chunk;
  if (j < nq) {
    is_sup = false;
    bq = lo + (j >> 2);
    chunk = j & 3;
  } else {
    int js = j - nq;
    if (js >= 5) return;
    is_sup = true;
    int u = x + 8 * js;
    bw = u >> 2;
    chunk = u & 3;
  }

  const int m0 = chunk * kCHUNK;
  const int mcnt = min(kCHUNK, kHW - m0);
  unsigned short* dst;

  if (is_sup) {
    const float* base = sup + (size_t)bw * kS * kC * kHW;
    for (int i = tid; i < kC * kCHUNK; i += 256) {
      int c = i / kCHUNK, mm = i % kCHUNK;
      float v = 0.f;
      if (mm < mcnt) {
        const float* p = base + (size_t)c * kHW + m0 + mm;
        float s = 0.f;
#pragma unroll
        for (int k = 0; k < kS; ++k) s += p[(size_t)k * kC * kHW];
        v = s * (1.f / kS);
      }
      img_t[mm * kLDT + c] = v;
    }
    dst = snT + (size_t)bw * kNP * kC;
  } else {
    const float* base = qry + (size_t)bq * kC * kHW;
    for (int i = tid; i < kC * kCHUNK; i += 256) {
      int c = i / kCHUNK, mm = i % kCHUNK;
      img_t[mm * kLDT + c] = (mm < mcnt) ? base[(size_t)c * kHW + m0 + mm] : 0.f;
    }
    dst = qnT + (size_t)bq * kMP * kC;
  }
  __syncthreads();

  if (tid < kCHUNK) {
    float ss = 0.f;
#pragma unroll
    for (int c = 0; c < kC; ++c) { float v = img_t[tid * kLDT + c]; ss += v * v; }
    inv[tid] = 1.f / fmaxf(sqrtf(ss), 1e-12f);
  }
  __syncthreads();

  for (int i8 = tid; i8 < kCHUNK * 8; i8 += 256) {
    int m = i8 >> 3, c8 = (i8 & 7) * 8;
    float sc = inv[m];
    union { unsigned short u[8]; uint4 v; } pk;
#pragma unroll
    for (int jj = 0; jj < 8; ++jj) {
      __hip_bfloat16 o = __float2bfloat16(img_t[m * kLDT + c8 + jj] * sc);
      pk.u[jj] = *reinterpret_cast<unsigned short*>(&o);
    }
    *reinterpret_cast<uint4*>(dst + ((size_t)(m0 + m) * kC + c8)) = pk.v;
  }
}

// ---- max helpers (validated; no inline asm on MFMA outputs — R12 lesson) ----
__device__ __forceinline__ float max16_v(const f32x16& a) {
  float m0 = fmaxf(fmaxf(a[0], a[1]), a[2]);
  float m1 = fmaxf(fmaxf(a[3], a[4]), a[5]);
  float m2 = fmaxf(fmaxf(a[6], a[7]), a[8]);
  float m3 = fmaxf(fmaxf(a[9], a[10]), a[11]);
  float m4 = fmaxf(fmaxf(a[12], a[13]), a[14]);
  return fmaxf(fmaxf(fmaxf(m0, m1), m2), fmaxf(fmaxf(m3, m4), a[15]));
}
__device__ __forceinline__ float max12_v(const f32x16& a) {
  float m0 = fmaxf(fmaxf(a[0], a[1]), a[2]);
  float m1 = fmaxf(fmaxf(a[3], a[4]), a[5]);
  float m2 = fmaxf(fmaxf(a[6], a[7]), a[8]);
  float m3 = fmaxf(fmaxf(a[9], a[10]), a[11]);
  return fmaxf(fmaxf(m0, m1), fmaxf(m2, m3));
}

// ---- main: block = (b,w, 4 q's). 512 thr / 8 waves; wave = (q, col-half):
//      7 col-tiles per wave (bf[7][4] = 112 VGPR reuse lever). A-tile staged
//      ONCE per block, shared by 4 q-tiles: staging traffic /4, per-nt compute
//      per wave ~900cyc vs 4 ds_reads (latency fully hidden). Grid 190 ->
//      single generation (<=256 CUs). Two barriers total. ----
__global__ __launch_bounds__(512) void dn4_main_k(const unsigned short* __restrict__ qnT,
                                                  const unsigned short* __restrict__ snT,
                                                  float* __restrict__ out) {
  __shared__ __align__(16) unsigned short As[kNP * kC];  // 57344 B
  __shared__ float part[8];
  const int tid = threadIdx.x;
  const int bid = blockIdx.x;

  const int bw = bid / kSPerBW;        // 0..9  (= b*5+w)
  const int s = bid % kSPerBW;         // 0..18 (q-quad)
  const int b = bw / kW;

  const int lane = tid & 63;
  const int lh = lane >> 5;
  const int lm = lane & 31;
  const int wid = tid >> 6;            // 0..7
  const int qi = wid >> 1;             // 0..3 within quad
  const int wp = wid & 1;              // col-half: ct = wp*7 + c
  const int q = s * 4 + qi;
  const bool valid = q < kQ;           // wave-uniform

  const unsigned short* sb = snT + (size_t)bw * kNP * kC;
  const char* sbase = (const char*)sb;

  // query fragments: 7 col-tiles x 4 K-frags (loads issued before staging)
  bf16x8 bf[7][4];
  if (valid) {
    const unsigned short* qb = qnT + (size_t)(b * kQ + q) * kMP * kC;
#pragma unroll
    for (int ct = 0; ct < 7; ++ct) {
      int m = (wp * 7 + ct) * 32 + lm;
#pragma unroll
      for (int kk = 0; kk < 4; ++kk)
        bf[ct][kk] = *reinterpret_cast<const bf16x8*>(qb + (size_t)m * kC + kk * 16 + lh * 8);
    }
  }

  // stage all 448 rows once: 3584 chunks = 7 rounds x 512 threads.
  // LDS linear dest, pre-swizzled source (involution, validated R5..R16).
#pragma unroll
  for (int it = 0; it < 7; ++it) {
    int L = it * 512 + tid;
    int srcj = (L & ~7) | ((L & 7) ^ ((L >> 3) & 7));
    __builtin_amdgcn_global_load_lds((gbl_u32*)(sbase + ((size_t)srcj << 4)),
                                     (lds_u32*)((char*)As + ((size_t)L << 4)), 16, 0, 0);
  }
  __syncthreads();   // staging + bf complete

  float rm[7] = {-INFINITY, -INFINITY, -INFINITY, -INFINITY,
                 -INFINITY, -INFINITY, -INFINITY};
  f32x16 z;
#pragma unroll
  for (int r = 0; r < 16; ++r) z[r] = 0.f;

  // 13 full nt-tiles (runtime loop: full unroll spills — R6 lesson)
#pragma unroll 1
  for (int nt = 0; nt < 13; ++nt) {
    bf16x8 af[4];
    int n = nt * 32 + lm;
#pragma unroll
    for (int kk = 0; kk < 4; ++kk) {
      int k16 = kk * 2 + lh;
      af[kk] = *reinterpret_cast<const bf16x8*>(As + ((size_t)(n * 8 + (k16 ^ (n & 7))) << 3));
    }
    if (valid) {
#pragma unroll
      for (int ct = 0; ct < 7; ++ct) {
        f32x16 acc = z;
#pragma unroll
        for (int kk = 0; kk < 4; ++kk)
          acc = __builtin_amdgcn_mfma_f32_32x32x16_bf16(af[kk], bf[ct][kk], acc, 0, 0, 0);
        rm[ct] = fmaxf(rm[ct], max16_v(acc));
      }
    }
  }

  // tail nt=13: rows 416..447; valid < 441 -> tile row <= 24.
  // row = (r&3)+8*(r>>2)+4*lh: lh0 invalid regs {13,14,15}, lh1 invalid {12..15}
  {
    bf16x8 af[4];
    int n = 13 * 32 + lm;
#pragma unroll
    for (int kk = 0; kk < 4; ++kk) {
      int k16 = kk * 2 + lh;
      af[kk] = *reinterpret_cast<const bf16x8*>(As + ((size_t)(n * 8 + (k16 ^ (n & 7))) << 3));
    }
    if (valid) {
#pragma unroll
      for (int ct = 0; ct < 7; ++ct) {
        f32x16 acc = z;
#pragma unroll
        for (int kk = 0; kk < 4; ++kk)
          acc = __builtin_amdgcn_mfma_f32_32x32x16_bf16(af[kk], bf[ct][kk], acc, 0, 0, 0);
        float t = max12_v(acc);
        if (lh == 0) t = fmaxf(t, acc[12]);  // row 24 still valid
        rm[ct] = fmaxf(rm[ct], t);
      }
    }
  }

  // reduce: combine complementary row-halves, sum this wave's 7x32 columns
  float ssum = 0.f;
  if (valid) {
#pragma unroll
    for (int ct = 0; ct < 7; ++ct)
      ssum += fmaxf(rm[ct], __shfl_xor(rm[ct], 32, 64));
#pragma unroll
    for (int off = 1; off < 32; off <<= 1) ssum += __shfl_xor(ssum, off, 64);
  }
  if (lane == 0) part[wid] = valid ? ssum : 0.f;
  __syncthreads();

  if (tid < 4) {
    int qq = s * 4 + tid;
    if (qq < kQ)
      out[(size_t)(b * kQ + qq) * kW + (bw % kW)] = part[2 * tid] + part[2 * tid + 1];
  }
}

extern "C" void kernel_launch(void* const* d_in, const int* in_sizes, int n_in,
                              void* d_out, int out_size, void* d_ws, size_t ws_size,
                              hipStream_t stream) {
  const float* sup = (const float*)d_in[0];
  const float* qry = (const float*)d_in[2];
  float* out = (float*)d_out;

  unsigned short* snT = (unsigned short*)d_ws;                 // 573,440 B
  unsigned short* qnT = snT + (size_t)kB * kW * kNP * kC;      // 8,601,600 B

  prep_k<<<kPrepGrid, 256, 0, stream>>>(sup, qry, snT, qnT);
  dn4_main_k<<<kGrid, 512, 0, stream>>>(qnT, snT, out);
}